// Round 7
// baseline (262.987 us; speedup 1.0000x reference)
//
#include <hip/hip_runtime.h>
#include <cstddef>

namespace {

constexpr int kV = 4096;

typedef float f32x16 __attribute__((ext_vector_type(16)));
typedef float f32x4  __attribute__((ext_vector_type(4)));
typedef short bf16x8 __attribute__((ext_vector_type(8)));

union U8 { unsigned u[4]; uint4 q; bf16x8 v; };

// round-to-nearest-even fp32->bf16, packed pair (a -> lo16, b -> hi16)
__device__ inline unsigned pk_bf16(float a, float b) {
    unsigned ua = __float_as_uint(a);
    unsigned ub = __float_as_uint(b);
    ua = (ua + 0x7FFFu + ((ua >> 16) & 1u)) >> 16;
    ub = (ub + 0x7FFFu + ((ub >> 16) & 1u)) & 0xFFFF0000u;
    return ua | ub;
}

// fp32 -> bf16 conversion of kernel_weights (re-done every launch; d_ws is
// re-poisoned before each timed replay).
__global__ void convW(const float* __restrict__ W, unsigned* __restrict__ Wb) {
    const int i = blockIdx.x * 256 + threadIdx.x;   // 32768 = 65536/2
    const float2 w2 = ((const float2*)W)[i];
    Wb[i] = pk_bf16(w2.x, w2.y);
}

// ---------------- Phase 1: one WAVE per v, no barriers ----------------
// Per wave: stream ck contiguously (dwordx4), shfl-gather signal (dwordx4),
// transpose both through wave-private LDS, 4x mfma 32x32x16, SH power
// epilogue, write z row (bf16) to d_ws. Two k-halves reuse one LDS buffer
// (in-order DS pipe + compiler lgkmcnt — R5-proven no-barrier pattern).
__global__ __launch_bounds__(256, 5)
void phase1(const float* __restrict__ signal,
            const int* __restrict__ pidx_g,
            const float* __restrict__ ck_g,
            unsigned short* __restrict__ zG)      // [32768][512] bf16
{
    // ckS: fp32 half-tile [local p][rn], +1 pad -> all reads/writes <=2-way.
    // sgS: bf16 k-pair dwords [pp][c]; pp<4 = local rows (pp,pp+4),
    //      pp>=4 = local rows (pp+4,pp+8) — A-frags use the SAME pairing.
    __shared__ float ckS[4][16][33];                        // 8.25 KB
    __shared__ __align__(16) unsigned sgS[4][8][64];        // 8 KB

    const int t = threadIdx.x;
    const int w = t >> 6, lane = t & 63;
    const int n31 = lane & 31, h = lane >> 5;
    const int r4 = lane >> 4, c16 = lane & 15;

    const size_t bv = (size_t)blockIdx.x * 4 + w;   // wave-private v
    const int b = (int)(bv >> 12);
    const float* sgb = signal + ((size_t)b << 12) * 64;
    const float* ckv = ck_g + bv * 1024;            // [32 p][32 rn]

    const int vsv = pidx_g[(bv * 32 + n31) * 2 + 1];  // lane p holds vs_p

    float (*ck_s)[33] = ckS[w];
    unsigned (*sg_s)[64] = sgS[w];

    f32x16 acc0, acc1;
    #pragma unroll
    for (int j = 0; j < 16; ++j) { acc0[j] = 0.f; acc1[j] = 0.f; }

    #pragma unroll
    for (int h2 = 0; h2 < 2; ++h2) {      // k-half: global rows 16h2..16h2+15
        // ck half-tile: 512 contiguous floats, 2 dwordx4/lane
        const float4* ckh = (const float4*)(ckv + h2 * 512);
        const float4 C0 = ckh[lane * 2];
        const float4 C1 = ckh[lane * 2 + 1];
        // signal gather: 4 dwordx4 (4 rows/instr via shfl row index)
        float4 S[4];
        #pragma unroll
        for (int k = 0; k < 4; ++k) {
            const int vs = __shfl(vsv, 16 * h2 + 4 * k + r4);
            S[k] = *(const float4*)(sgb + (size_t)vs * 64 + c16 * 4);
        }

        // stage ck: lane holds local row l>>2, cols 8*(l&3)..+8
        {
            const int r = lane >> 2, cb = 8 * (lane & 3);
            ck_s[r][cb + 0] = C0.x; ck_s[r][cb + 1] = C0.y;
            ck_s[r][cb + 2] = C0.z; ck_s[r][cb + 3] = C0.w;
            ck_s[r][cb + 4] = C1.x; ck_s[r][cb + 5] = C1.y;
            ck_s[r][cb + 6] = C1.z; ck_s[r][cb + 7] = C1.w;
        }
        // stage signal k-pairs: (S0,S1) = local rows (r4, r4+4) -> pp=r4;
        //                       (S2,S3) = rows (r4+8, r4+12)    -> pp=4+r4
        {
            uint4 d0, d1;
            d0.x = pk_bf16(S[0].x, S[1].x); d0.y = pk_bf16(S[0].y, S[1].y);
            d0.z = pk_bf16(S[0].z, S[1].z); d0.w = pk_bf16(S[0].w, S[1].w);
            d1.x = pk_bf16(S[2].x, S[3].x); d1.y = pk_bf16(S[2].y, S[3].y);
            d1.z = pk_bf16(S[2].z, S[3].z); d1.w = pk_bf16(S[2].w, S[3].w);
            *(uint4*)&sg_s[r4][c16 * 4]     = d0;
            *(uint4*)&sg_s[4 + r4][c16 * 4] = d1;
        }

        // frags: k-slot dword j2 of lane h <-> local rows (j2+8h, j2+8h+4)
        U8 A, B0, B1;
        #pragma unroll
        for (int j2 = 0; j2 < 4; ++j2) {
            const int rho = j2 + 8 * h;
            A.u[j2]  = pk_bf16(ck_s[rho][n31], ck_s[rho + 4][n31]);
            B0.u[j2] = sg_s[4 * h + j2][n31];
            B1.u[j2] = sg_s[4 * h + j2][n31 + 32];
        }
        acc0 = __builtin_amdgcn_mfma_f32_32x32x16_bf16(A.v, B0.v, acc0, 0, 0, 0);
        acc1 = __builtin_amdgcn_mfma_f32_32x32x16_bf16(A.v, B1.v, acc1, 0, 0, 0);
    }

    // C-layout: col=lane&31 (=c), row=(reg&3)+8*(reg>>2)+4*h (=rn=r*16+n).
    #pragma unroll
    for (int ct = 0; ct < 2; ++ct) {
        const f32x16 a = ct ? acc1 : acc0;
        float s[16];
        #pragma unroll
        for (int j = 0; j < 16; ++j) s[j] = a[j] * a[j];
        // h=0 rows {0-3,8-11,16-19,24-27}; h=1 rows {4-7,12-15,20-23,28-31}
        const float o00 = s[0], o10 = s[1] + s[2] + s[3];
        const float o20 = s[4], o30 = s[5] + s[6] + s[7];
        const float o01 = s[8], o11 = s[9] + s[10] + s[11];
        const float o21 = s[12], o31 = s[13] + s[14] + s[15];
        const float x0 = s[0] + s[1] + s[2] + s[3];
        const float x1 = s[4] + s[5] + s[6] + s[7];
        const float x2 = s[8] + s[9] + s[10] + s[11];
        const float x3 = s[12] + s[13] + s[14] + s[15];
        const float e0 = __shfl_xor(h ? x0 : o20, 32);
        const float e1 = __shfl_xor(h ? x1 : o30, 32);
        const float e2 = __shfl_xor(h ? x2 : o21, 32);
        const float e3 = __shfl_xor(h ? x3 : o31, 32);
        if (h == 0) {
            const float z00 = sqrtf(fmaxf(o00,      1e-4f));
            const float z10 = sqrtf(fmaxf(o10,      1e-4f));
            const float z20 = sqrtf(fmaxf(o20 + e0, 1e-4f));
            const float z30 = sqrtf(fmaxf(o30 + e1, 1e-4f));
            const float z01 = sqrtf(fmaxf(o01,      1e-4f));
            const float z11 = sqrtf(fmaxf(o11,      1e-4f));
            const float z21 = sqrtf(fmaxf(o21 + e2, 1e-4f));
            const float z31 = sqrtf(fmaxf(o31 + e3, 1e-4f));
            uint4 d;
            d.x = pk_bf16(z00, z10);
            d.y = pk_bf16(z20, z30);
            d.z = pk_bf16(z01, z11);
            d.w = pk_bf16(z21, z31);
            // z[bv][j], j = c*8 + r*4 + l; 32 lanes x 16 B contiguous
            ((uint4*)(zG + bv * 512))[n31 + 32 * ct] = d;
        }
    }
}

// ------- Phase 2: out = relu(W z + b). MFMA 16x16x32, wave = 16 v x 128 i --
__global__ __launch_bounds__(256, 4)
void phase2(const unsigned short* __restrict__ zG,
            const unsigned short* __restrict__ Wb,
            const float* __restrict__ bias,
            float* __restrict__ out)
{
    const int t = threadIdx.x;
    const int w = t >> 6, lane = t & 63;
    const int m15 = lane & 15;          // A row (v) AND D col (i) index
    const int q   = lane >> 4;          // k-quad
    const int v0  = blockIdx.x * 64 + w * 16;

    f32x4 acc[8];
    #pragma unroll
    for (int nt = 0; nt < 8; ++nt)
        #pragma unroll
        for (int j = 0; j < 4; ++j) acc[nt][j] = 0.f;

    #pragma unroll 2
    for (int ks = 0; ks < 16; ++ks) {
        U8 Az;
        Az.q = *(const uint4*)&zG[(size_t)(v0 + m15) * 512 + ks * 32 + q * 8];
        #pragma unroll
        for (int nt = 0; nt < 8; ++nt) {
            U8 Bw;   // Wb L2-hot (128 KB, reused by every block)
            Bw.q = *(const uint4*)&Wb[(size_t)(nt * 16 + m15) * 512 + ks * 32 + q * 8];
            acc[nt] = __builtin_amdgcn_mfma_f32_16x16x32_bf16(Az.v, Bw.v, acc[nt], 0, 0, 0);
        }
    }
    #pragma unroll
    for (int nt = 0; nt < 8; ++nt) {
        const float bi = bias[nt * 16 + m15];
        #pragma unroll
        for (int reg = 0; reg < 4; ++reg) {   // D row = q*4+reg = v offset
            out[(size_t)(v0 + q * 4 + reg) * 128 + nt * 16 + m15] =
                fmaxf(acc[nt][reg] + bi, 0.f);
        }
    }
}

} // namespace

extern "C" void kernel_launch(void* const* d_in, const int* in_sizes, int n_in,
                              void* d_out, int out_size, void* d_ws, size_t ws_size,
                              hipStream_t stream) {
    const float* signal = (const float*)d_in[0];
    const int*   pidx   = (const int*)d_in[1];
    const float* ck     = (const float*)d_in[2];
    const float* W      = (const float*)d_in[3];
    const float* bias   = (const float*)d_in[4];
    float* out = (float*)d_out;

    // d_ws layout: [0, 32 MB) z (bf16), [32 MB, +128 KB) Wb (bf16)
    unsigned short* zG = (unsigned short*)d_ws;
    unsigned* Wb = (unsigned*)((char*)d_ws + ((size_t)32 << 20));

    convW<<<dim3(128), dim3(256), 0, stream>>>(W, Wb);
    phase1<<<dim3(8192), dim3(256), 0, stream>>>(signal, pidx, ck, zG);
    phase2<<<dim3(512), dim3(256), 0, stream>>>(
        zG, (const unsigned short*)Wb, bias, out);
}